// Round 10
// baseline (3186.110 us; speedup 1.0000x reference)
//
#include <hip/hip_runtime.h>
#include <stdint.h>
#include <string.h>

// Problem constants (match reference setup_inputs)
constexpr int S = 64, H = 294, W = 518;
constexpr int HW = H * W;            // 152292
constexpr int N = S * HW;            // 9746688
// Padded per-frame key stride so frame key regions are 64B-line-disjoint
// (152296*8 = 64*19037): no cache line is touched by two frames.
constexpr int HWP = HW + 4;

constexpr int BLK = 256;
constexpr int PB  = (HW + BLK - 1) / BLK;   // 595 prep items per frame
// Tiled gather geometry: 64x4-pixel tiles.
constexpr int TW = 64, TH = 4;
constexpr int TX = (W + TW - 1) / TW;       // 9
constexpr int TY = (H + TH - 1) / TH;       // 74
constexpr int GB = TX * TY;                 // 666 gather items per frame
constexpr int NXCD = 8;
constexpr int FPX  = S / NXCD;              // 8 frames per XCD queue
constexpr int ITEMS = FPX * PB + FPX * GB;  // 10088 items per queue

// Missed-pixel depth sentinel: must stay FINITE under bf16 rounding too
// (FLT_MAX rounds to +inf in bf16 -> harness absmax does inf-inf = nan).
#define DEPTH_MISS 1.0e30f

typedef unsigned long long u64;
constexpr u64 KEY_SENT = 0xFFFFFFFFFFFFFFFFull;

// ---- monotone float<->uint encoding for atomicMin on uint ----
__device__ __forceinline__ uint32_t enc_f32(float f) {
  uint32_t u = __float_as_uint(f);
  return (u & 0x80000000u) ? ~u : (u | 0x80000000u);
}
__device__ __forceinline__ float dec_f32(uint32_t u) {
  uint32_t b = (u & 0x80000000u) ? (u ^ 0x80000000u) : ~u;
  return __uint_as_float(b);
}

struct Proj {
  float z, du, dv;
  int u0, v0, u1, v1;
  bool valid;
};

// Deterministic op sequence (explicit fma) -> identical results wherever a
// point's projection is recomputed (hit test is exact equality on z).
__device__ __forceinline__ Proj project(float px, float py, float pz,
                                        const float* __restrict__ E,
                                        const float* __restrict__ K) {
  Proj r;
  float cx = __fmaf_rn(E[0], px, __fmaf_rn(E[1], py, __fmaf_rn(E[2], pz, E[3])));
  float cy = __fmaf_rn(E[4], px, __fmaf_rn(E[5], py, __fmaf_rn(E[6], pz, E[7])));
  float cz = __fmaf_rn(E[8], px, __fmaf_rn(E[9], py, __fmaf_rn(E[10], pz, E[11])));
  float uh = __fmaf_rn(K[0], cx, __fmaf_rn(K[1], cy, __fmul_rn(K[2], cz)));
  float vh = __fmaf_rn(K[3], cx, __fmaf_rn(K[4], cy, __fmul_rn(K[5], cz)));
  float wh = __fmaf_rn(K[6], cx, __fmaf_rn(K[7], cy, __fmul_rn(K[8], cz)));
  float d  = __fadd_rn(wh, 1e-7f);
  float u  = __fdiv_rn(uh, d);
  float v  = __fdiv_rn(vh, d);
  r.z = cz;
  r.valid = (cz > 0.0f) & (u >= 0.0f) & (u < (float)W) & (v >= 0.0f) & (v < (float)H);
  u = fminf(fmaxf(u, 0.0f), (float)(W - 1));
  v = fminf(fmaxf(v, 0.0f), (float)(H - 1));
  int u0 = (int)u;  // u >= 0, so trunc == floor
  int v0 = (int)v;
  r.u0 = u0; r.v0 = v0;
  r.u1 = min(u0 + 1, W - 1);
  r.v1 = min(v0 + 1, H - 1);
  r.du = __fadd_rn(u, -(float)u0);
  r.dv = __fadd_rn(v, -(float)v0);
  return r;
}

__device__ __forceinline__ u64 f2_bits(float2 v) {
  u64 b; memcpy(&b, &v, 8); return b;
}

// Per-XCD-queue item decode. Order: P(f0) P(f1) G(f0) P(f2) G(f1) ...
// P(f7) G(f6) G(f7) -> one frame of prep lead before each gather.
__device__ __forceinline__ void decode_item(int i, bool& isP, int& f, int& j) {
  if (i < 2 * PB) { isP = true; f = i / PB; j = i - f * PB; return; }
  const int k = i - 2 * PB;
  const int b = k / (PB + GB);
  if (b < FPX - 2) {
    const int r = k - b * (PB + GB);
    if (r < GB) { isP = false; f = b; j = r; }
    else        { isP = true;  f = b + 2; j = r - GB; }
    return;
  }
  const int g = k - (FPX - 2) * (PB + GB);
  isP = false; f = (FPX - 2) + g / GB; j = g - (g / GB) * GB;
}

// ============ FUSED persistent pipeline (prep || gather per XCD) ============
// Correctness notes (independent of blockIdx->XCD mapping):
//  * keys: device-scope atomicMin executes at the coherence point; frame key
//    regions are line-disjoint (HWP pad); gather reads a frame's key lines
//    only after acquiring done[s]==PB, so first-touch fetches see final mins.
//  * rec: written with AGENT-scope atomic stores (write-through; no L2 holds
//    dirty record lines), read with plain loads after the acquire.
//  * done[s] is incremented AFTER __syncthreads() (compiler drains vmcnt
//    before s_barrier), so every item's atomics/stores are complete-at-
//    coherence-point before its increment is visible.
//  * No deadlock: gather items are dequeued only after all of that frame's
//    prep items were dequeued by resident blocks, which finish regardless
//    of spinners (all are co-resident or the queue is already drained).
__global__ __launch_bounds__(256) void k_fused(
    const float* __restrict__ wp, const float* __restrict__ extr,
    const float* __restrict__ intr, const float* __restrict__ images,
    const float* __restrict__ conf, u64* __restrict__ keys,
    float2* __restrict__ rec, uint32_t* __restrict__ qc,
    uint32_t* __restrict__ done, float* __restrict__ out) {
  __shared__ float4   sc_[TH + 1][TW + 1];
  __shared__ float2   sd_[TH + 1][TW + 1];
  __shared__ uint32_t sh_[TH + 1][TW + 1];
  __shared__ int s_item;

  const int t = threadIdx.x;
  const int xq = blockIdx.x & (NXCD - 1);   // queue id (co-resident L2 group)

  for (;;) {
    __syncthreads();   // protects s_item and LDS arrays across iterations
    if (t == 0)
      s_item = (int)__hip_atomic_fetch_add(&qc[xq], 1u, __ATOMIC_RELAXED,
                                           __HIP_MEMORY_SCOPE_AGENT);
    __syncthreads();
    const int it = s_item;
    if (it >= ITEMS) break;

    bool isP; int f, j;
    decode_item(it, isP, f, j);
    const int s = xq * FPX + f;

    if (isP) {
      // ---------------- prep item: 256 points ----------------
      const int p = j * BLK + t;
      if (p < HW) {
        const float* E = extr + s * 12;
        const float* K = intr + s * 9;
        const int idx = s * HW + p;
        Proj pr = project(wp[idx*3], wp[idx*3+1], wp[idx*3+2], E, K);
        const size_t pix = (size_t)s * HWP + pr.v0 * W + pr.u0;
        atomicMin(&keys[pix], ((u64)enc_f32(pr.z) << 32) | (uint32_t)p);

        const size_t ib = (size_t)s * 3 * HW + p;
        const float vf = pr.valid ? 1.f : 0.f;
        u64* r2 = (u64*)(rec + (size_t)idx * 4);
        __hip_atomic_store(&r2[0], f2_bits(make_float2(vf*images[ib],      vf*images[ib+HW])),
                           __ATOMIC_RELAXED, __HIP_MEMORY_SCOPE_AGENT);
        __hip_atomic_store(&r2[1], f2_bits(make_float2(vf*images[ib+2*HW], vf*conf[idx])),
                           __ATOMIC_RELAXED, __HIP_MEMORY_SCOPE_AGENT);
        __hip_atomic_store(&r2[2], f2_bits(make_float2(vf*pr.du,           vf*pr.dv)),
                           __ATOMIC_RELAXED, __HIP_MEMORY_SCOPE_AGENT);
      }
      __syncthreads();   // drains vmcnt for ALL threads of the block
      if (t == 0)
        __hip_atomic_fetch_add(&done[s], 1u, __ATOMIC_RELEASE,
                               __HIP_MEMORY_SCOPE_AGENT);
    } else {
      // ---------------- gather item: one 64x4 tile ----------------
      if (t == 0) {
        while (__hip_atomic_load(&done[s], __ATOMIC_ACQUIRE,
                                 __HIP_MEMORY_SCOPE_AGENT) < (uint32_t)PB)
          __builtin_amdgcn_s_sleep(2);
      }
      __syncthreads();

      const int ty = j / TX, tx = j - ty * TX;
      const int x0 = tx * TW, y0 = ty * TH;
      const u64* kfr = keys + (size_t)s * HWP;
      const float2* rfr = rec + (size_t)s * HW * 4;

      for (int l = t; l < (TH + 1) * (TW + 1); l += BLK) {
        const int rr = l / (TW + 1), cc2 = l - rr * (TW + 1);
        const int yy = y0 - 1 + rr, xx = x0 - 1 + cc2;
        float4 cc = make_float4(0.f, 0.f, 0.f, 0.f);
        float2 dd = make_float2(0.f, 0.f);
        uint32_t hi = 0xFFFFFFFFu;
        if (yy >= 0 && yy < H && xx >= 0 && xx < W) {
          const u64 k = kfr[yy * W + xx];
          if (k != KEY_SENT) {
            hi = (uint32_t)(k >> 32);
            const float2* q = rfr + (size_t)(uint32_t)k * 4;
            const float2 a = q[0], b = q[1], e = q[2];
            cc = make_float4(a.x, a.y, b.x, b.y);
            dd = e;
          }
        }
        sc_[rr][cc2] = cc; sd_[rr][cc2] = dd; sh_[rr][cc2] = hi;
      }
      __syncthreads();

      const int c = t % TW, r = t / TW;   // r in [0,TH)
      const int x = x0 + c, y = y0 + r;
      if (x < W && y < H) {
        const bool ex = (x == W - 1);
        const bool ey = (y == H - 1);
        const float4 cC = sc_[r + 1][c + 1]; const float2 dC = sd_[r + 1][c + 1];
        const float4 cU = sc_[r][c + 1];     const float2 dU = sd_[r][c + 1];
        const float4 cL = sc_[r + 1][c];     const float2 dL = sd_[r + 1][c];
        const float4 cD = sc_[r][c];         const float2 dD = sd_[r][c];
        const uint32_t hi = sh_[r + 1][c + 1];

        const float wC = (ex ? 1.f : 1.f - dC.x) * (ey ? 1.f : 1.f - dC.y);
        const float wU = (ex ? 1.f : 1.f - dU.x) * dU.y;
        const float wL = dL.x * (ey ? 1.f : 1.f - dL.y);
        const float wD = dD.x * dD.y;

        // reference splat-loop order: C(w00), U(w01), L(w10), D(w11)
        const float ar = wC*cC.x + wU*cU.x + wL*cL.x + wD*cD.x;
        const float ag = wC*cC.y + wU*cU.y + wL*cL.y + wD*cD.y;
        const float ab = wC*cC.z + wU*cU.z + wL*cL.z + wD*cD.z;
        const float ac = wC*cC.w + wU*cU.w + wL*cL.w + wD*cD.w;
        const bool over = (ar > 1.f) | (ag > 1.f) | (ab > 1.f);

        float* rgb   = out;
        float* depth = out + (size_t)3 * N;
        float* cbuf  = out + (size_t)4 * N;
        float* mask  = out + (size_t)5 * N;
        const int p = y * W + x;
        const size_t ob = (size_t)s * 3 * HW + p;
        rgb[ob]          = fminf(fmaxf(ar, 0.f), 1.f);
        rgb[ob + HW]     = fminf(fmaxf(ag, 0.f), 1.f);
        rgb[ob + 2*HW]   = fminf(fmaxf(ab, 0.f), 1.f);
        const int i = s * HW + p;
        const bool missed = (hi == 0xFFFFFFFFu);
        depth[i] = missed ? DEPTH_MISS : dec_f32(hi);
        cbuf[i]  = ac;
        mask[i]  = (!missed && !over) ? 1.f : 0.f;
      }
    }
  }
}

// ============== Fallback A1: round-9 two-kernel path (proven) ==============

template <int REC>
__global__ __launch_bounds__(256) void k_prep(
    const float* __restrict__ wp, const float* __restrict__ extr,
    const float* __restrict__ intr, const float* __restrict__ images,
    const float* __restrict__ conf, u64* __restrict__ keys,
    float2* __restrict__ rec) {
  const int nb = PB * S;
  const int o = blockIdx.x;
  const int wg = (o % NXCD) * (nb / NXCD) + o / NXCD;
  const int s  = wg / PB;
  const int p  = (wg - s * PB) * BLK + threadIdx.x;
  if (p >= HW) return;
  const float* E = extr + s * 12;
  const float* K = intr + s * 9;
  const int idx = s * HW + p;
  Proj pr = project(wp[idx*3], wp[idx*3+1], wp[idx*3+2], E, K);
  const size_t pix = (size_t)s * HW + pr.v0 * W + pr.u0;
  atomicMin(&keys[pix], ((u64)enc_f32(pr.z) << 32) | (uint32_t)p);
  const size_t ib = (size_t)s * 3 * HW + p;
  const float vf = pr.valid ? 1.f : 0.f;
  float2* r2 = rec + (size_t)idx * REC;
  r2[0] = make_float2(vf * images[ib],          vf * images[ib + HW]);
  r2[1] = make_float2(vf * images[ib + 2 * HW], vf * conf[idx]);
  r2[2] = make_float2(vf * pr.du,               vf * pr.dv);
}

template <int REC>
__global__ __launch_bounds__(256) void k_gather4(
    const u64* __restrict__ keys, const float2* __restrict__ rec,
    float* __restrict__ out) {
  __shared__ float4   sc[TH + 1][TW + 1];
  __shared__ float2   sd[TH + 1][TW + 1];
  __shared__ uint32_t sh[TH + 1][TW + 1];
  const int nb2 = GB * S;
  const int o = blockIdx.x;
  const int wg = (o % NXCD) * (nb2 / NXCD) + o / NXCD;
  const int s   = wg / GB;
  const int tid = wg - s * GB;
  const int ty  = tid / TX, tx = tid - ty * TX;
  const int x0  = tx * TW, y0 = ty * TH;
  const int t   = threadIdx.x;
  const u64* kfr = keys + (size_t)s * HW;
  const float2* rfr = rec + (size_t)s * HW * REC;

  for (int l = t; l < (TH + 1) * (TW + 1); l += BLK) {
    const int r = l / (TW + 1), c = l - r * (TW + 1);
    const int yy = y0 - 1 + r, xx = x0 - 1 + c;
    float4 cc = make_float4(0.f, 0.f, 0.f, 0.f);
    float2 dd = make_float2(0.f, 0.f);
    uint32_t hi = 0xFFFFFFFFu;
    if (yy >= 0 && yy < H && xx >= 0 && xx < W) {
      const u64 k = kfr[yy * W + xx];
      if (k != KEY_SENT) {
        hi = (uint32_t)(k >> 32);
        const float2* q = rfr + (size_t)(uint32_t)k * REC;
        const float2 a = q[0], b = q[1], e = q[2];
        cc = make_float4(a.x, a.y, b.x, b.y);
        dd = e;
      }
    }
    sc[r][c] = cc; sd[r][c] = dd; sh[r][c] = hi;
  }
  __syncthreads();

  const int c = t % TW, r = t / TW;
  const int x = x0 + c, y = y0 + r;
  if (x >= W || y >= H) return;
  const bool ex = (x == W - 1);
  const bool ey = (y == H - 1);
  const float4 cC = sc[r + 1][c + 1]; const float2 dC = sd[r + 1][c + 1];
  const float4 cU = sc[r][c + 1];     const float2 dU = sd[r][c + 1];
  const float4 cL = sc[r + 1][c];     const float2 dL = sd[r + 1][c];
  const float4 cD = sc[r][c];         const float2 dD = sd[r][c];
  const uint32_t hi = sh[r + 1][c + 1];
  const float wC = (ex ? 1.f : 1.f - dC.x) * (ey ? 1.f : 1.f - dC.y);
  const float wU = (ex ? 1.f : 1.f - dU.x) * dU.y;
  const float wL = dL.x * (ey ? 1.f : 1.f - dL.y);
  const float wD = dD.x * dD.y;
  const float ar = wC*cC.x + wU*cU.x + wL*cL.x + wD*cD.x;
  const float ag = wC*cC.y + wU*cU.y + wL*cL.y + wD*cD.y;
  const float ab = wC*cC.z + wU*cU.z + wL*cL.z + wD*cD.z;
  const float ac = wC*cC.w + wU*cU.w + wL*cL.w + wD*cD.w;
  const bool over = (ar > 1.f) | (ag > 1.f) | (ab > 1.f);

  float* rgb   = out;
  float* depth = out + (size_t)3 * N;
  float* cbuf  = out + (size_t)4 * N;
  float* mask  = out + (size_t)5 * N;
  const int p = y * W + x;
  const size_t ob = (size_t)s * 3 * HW + p;
  rgb[ob]          = fminf(fmaxf(ar, 0.f), 1.f);
  rgb[ob + HW]     = fminf(fmaxf(ag, 0.f), 1.f);
  rgb[ob + 2 * HW] = fminf(fmaxf(ab, 0.f), 1.f);
  const int i = s * HW + p;
  const bool missed = (hi == 0xFFFFFFFFu);
  depth[i] = missed ? DEPTH_MISS : dec_f32(hi);
  cbuf[i]  = ac;
  mask[i]  = (!missed && !over) ? 1.f : 0.f;
}

// ================== Tier C (round-3 scatter, proven, no ws) ==================

__global__ __launch_bounds__(256) void k_depth(
    const float* __restrict__ wp, const float* __restrict__ extr,
    const float* __restrict__ intr, uint32_t* __restrict__ denc) {
  const int s = blockIdx.y;
  const int p = blockIdx.x * blockDim.x + threadIdx.x;
  if (p >= HW) return;
  const float* E = extr + s * 12;
  const float* K = intr + s * 9;
  const int idx = s * HW + p;
  Proj pr = project(wp[idx*3], wp[idx*3+1], wp[idx*3+2], E, K);
  const int pix = s * HW + pr.v0 * W + pr.u0;
  atomicMin(&denc[pix], enc_f32(pr.z));
}

__global__ __launch_bounds__(256) void k_splat(
    const float* __restrict__ wp, const float* __restrict__ extr,
    const float* __restrict__ intr, const float* __restrict__ images,
    const float* __restrict__ conf, const uint32_t* __restrict__ denc,
    float* __restrict__ rgb_buf, float* __restrict__ conf_buf) {
  const int s = blockIdx.y;
  const int p = blockIdx.x * blockDim.x + threadIdx.x;
  if (p >= HW) return;
  const float* E = extr + s * 12;
  const float* K = intr + s * 9;
  const int idx = s * HW + p;
  Proj pr = project(wp[idx*3], wp[idx*3+1], wp[idx*3+2], E, K);
  const int pix0 = s * HW + pr.v0 * W + pr.u0;
  if (!pr.valid) return;
  if (enc_f32(pr.z) != denc[pix0]) return;
  const float du = pr.du, dv = pr.dv;
  const float w00 = (1.0f - du) * (1.0f - dv);
  const float w01 = (1.0f - du) * dv;
  const float w10 = du * (1.0f - dv);
  const float w11 = du * dv;
  const int ibase = s * 3 * HW + p;
  const float r = images[ibase];
  const float g = images[ibase + HW];
  const float b = images[ibase + 2 * HW];
  const float cf = conf[idx];
  const int sbase = s * HW;
  const int cbase = s * 3 * HW;
  #define SPLAT(WGT, PU, PV)                                              \
    if ((WGT) != 0.0f) {                                                  \
      const int q = (PV) * W + (PU);                                      \
      unsafeAtomicAdd(&rgb_buf[cbase + q],          (WGT) * r);           \
      unsafeAtomicAdd(&rgb_buf[cbase + HW + q],     (WGT) * g);           \
      unsafeAtomicAdd(&rgb_buf[cbase + 2 * HW + q], (WGT) * b);           \
      unsafeAtomicAdd(&conf_buf[sbase + q],         (WGT) * cf);          \
    }
  SPLAT(w00, pr.u0, pr.v0)
  SPLAT(w01, pr.u0, pr.v1)
  SPLAT(w10, pr.u1, pr.v0)
  SPLAT(w11, pr.u1, pr.v1)
  #undef SPLAT
}

__global__ __launch_bounds__(256) void k_final(float* __restrict__ out) {
  const int s = blockIdx.y;
  const int p = blockIdx.x * blockDim.x + threadIdx.x;
  if (p >= HW) return;
  float* rgb = out;
  float* depth = out + (size_t)3 * N;
  float* mask = out + (size_t)5 * N;
  uint32_t* denc = (uint32_t*)depth;
  const int cbase = s * 3 * HW + p;
  const float r = rgb[cbase];
  const float g = rgb[cbase + HW];
  const float b = rgb[cbase + 2 * HW];
  const bool over = (r > 1.0f) | (g > 1.0f) | (b > 1.0f);
  rgb[cbase]          = fminf(fmaxf(r, 0.0f), 1.0f);
  rgb[cbase + HW]     = fminf(fmaxf(g, 0.0f), 1.0f);
  rgb[cbase + 2 * HW] = fminf(fmaxf(b, 0.0f), 1.0f);
  const int i = s * HW + p;
  const uint32_t u = denc[i];
  const bool missed = (u == 0xFFFFFFFFu);
  depth[i] = missed ? DEPTH_MISS : dec_f32(u);
  mask[i] = (!missed && !over) ? 1.0f : 0.0f;
}

extern "C" void kernel_launch(void* const* d_in, const int* in_sizes, int n_in,
                              void* d_out, int out_size, void* d_ws, size_t ws_size,
                              hipStream_t stream) {
  const float* images = (const float*)d_in[0];
  const float* wp     = (const float*)d_in[1];
  const float* conf   = (const float*)d_in[2];
  const float* extr   = (const float*)d_in[3];
  const float* intr   = (const float*)d_in[4];
  float* out = (float*)d_out;

  const size_t cnt_bytes   = 4096;                            // qc[8]+done[64]
  const size_t keysp_bytes = (size_t)S * HWP * sizeof(u64);   // padded keys
  const size_t keys_bytes  = (size_t)N * sizeof(u64);
  const size_t rec4_bytes  = (size_t)N * 4 * sizeof(float2);  // 312 MB
  dim3 blk(BLK, 1, 1);

  if (ws_size >= cnt_bytes + keysp_bytes + rec4_bytes) {
    // Fused persistent pipeline: gather hides under the atomic wall.
    uint32_t* cnt  = (uint32_t*)d_ws;
    u64*      keys = (u64*)((char*)d_ws + cnt_bytes);
    float2*   rec  = (float2*)((char*)d_ws + cnt_bytes + keysp_bytes);
    hipMemsetAsync(cnt, 0, cnt_bytes, stream);
    hipMemsetAsync(keys, 0xFF, keysp_bytes, stream);
    hipLaunchKernelGGL(k_fused, dim3(2048), blk, 0, stream, wp, extr, intr,
                       images, conf, keys, rec, cnt, cnt + 8, out);
  } else if (ws_size >= keys_bytes + rec4_bytes) {
    // Round-9 two-kernel path (proven).
    u64*    keys = (u64*)d_ws;
    float2* rec  = (float2*)((char*)d_ws + keys_bytes);
    hipMemsetAsync(keys, 0xFF, keys_bytes, stream);
    hipLaunchKernelGGL((k_prep<4>), dim3(PB * S), blk, 0, stream, wp, extr,
                       intr, images, conf, keys, rec);
    hipLaunchKernelGGL((k_gather4<4>), dim3(GB * S), blk, 0, stream, keys, rec, out);
  } else {
    // Tier C: round-3 scatter path.
    float*    rgb_buf  = out;
    uint32_t* denc     = (uint32_t*)(out + (size_t)3 * N);
    float*    conf_buf = out + (size_t)4 * N;
    hipMemsetAsync(rgb_buf, 0, (size_t)3 * N * sizeof(float), stream);
    hipMemsetAsync(denc, 0xFF, (size_t)N * sizeof(uint32_t), stream);
    hipMemsetAsync(conf_buf, 0, (size_t)N * sizeof(float), stream);
    dim3 grd(PB, S, 1);
    hipLaunchKernelGGL(k_depth, grd, blk, 0, stream, wp, extr, intr, denc);
    hipLaunchKernelGGL(k_splat, grd, blk, 0, stream, wp, extr, intr, images,
                       conf, denc, rgb_buf, conf_buf);
    hipLaunchKernelGGL(k_final, grd, blk, 0, stream, out);
  }
}

// Round 11
// 2103.970 us; speedup vs baseline: 1.5143x; 1.5143x over previous
//
#include <hip/hip_runtime.h>
#include <stdint.h>

// Problem constants (match reference setup_inputs)
constexpr int S = 64, H = 294, W = 518;
constexpr int HW = H * W;            // 152292
constexpr int N = S * HW;            // 9746688
// Padded per-frame key stride so frame key regions are 64B-line-disjoint.
constexpr int HWP = HW + 4;

constexpr int BLK = 256;
constexpr int PB  = (HW + BLK - 1) / BLK;   // 595 prep items per frame
// Tiled gather geometry: 64x4-pixel tiles.
constexpr int TW = 64, TH = 4;
constexpr int TX = (W + TW - 1) / TW;       // 9
constexpr int TY = (H + TH - 1) / TH;       // 74
constexpr int GB = TX * TY;                 // 666 gather items per frame
constexpr int NXCD = 8;
constexpr int FPX  = S / NXCD;              // 8 frames per XCD queue
constexpr int ITEMS = FPX * PB + FPX * GB;  // 10088 items per queue

// Missed-pixel depth sentinel: must stay FINITE under bf16 rounding too
// (FLT_MAX rounds to +inf in bf16 -> harness absmax does inf-inf = nan).
#define DEPTH_MISS 1.0e30f

typedef unsigned long long u64;
constexpr u64 KEY_SENT = 0xFFFFFFFFFFFFFFFFull;

// ---- monotone float<->uint encoding for atomicMin on uint ----
__device__ __forceinline__ uint32_t enc_f32(float f) {
  uint32_t u = __float_as_uint(f);
  return (u & 0x80000000u) ? ~u : (u | 0x80000000u);
}
__device__ __forceinline__ float dec_f32(uint32_t u) {
  uint32_t b = (u & 0x80000000u) ? (u ^ 0x80000000u) : ~u;
  return __uint_as_float(b);
}

struct Proj {
  float z, du, dv;
  int u0, v0, u1, v1;
  bool valid;
};

// Deterministic op sequence (explicit fma) -> identical results wherever a
// point's projection is recomputed (hit test is exact equality on z).
__device__ __forceinline__ Proj project(float px, float py, float pz,
                                        const float* __restrict__ E,
                                        const float* __restrict__ K) {
  Proj r;
  float cx = __fmaf_rn(E[0], px, __fmaf_rn(E[1], py, __fmaf_rn(E[2], pz, E[3])));
  float cy = __fmaf_rn(E[4], px, __fmaf_rn(E[5], py, __fmaf_rn(E[6], pz, E[7])));
  float cz = __fmaf_rn(E[8], px, __fmaf_rn(E[9], py, __fmaf_rn(E[10], pz, E[11])));
  float uh = __fmaf_rn(K[0], cx, __fmaf_rn(K[1], cy, __fmul_rn(K[2], cz)));
  float vh = __fmaf_rn(K[3], cx, __fmaf_rn(K[4], cy, __fmul_rn(K[5], cz)));
  float wh = __fmaf_rn(K[6], cx, __fmaf_rn(K[7], cy, __fmul_rn(K[8], cz)));
  float d  = __fadd_rn(wh, 1e-7f);
  float u  = __fdiv_rn(uh, d);
  float v  = __fdiv_rn(vh, d);
  r.z = cz;
  r.valid = (cz > 0.0f) & (u >= 0.0f) & (u < (float)W) & (v >= 0.0f) & (v < (float)H);
  u = fminf(fmaxf(u, 0.0f), (float)(W - 1));
  v = fminf(fmaxf(v, 0.0f), (float)(H - 1));
  int u0 = (int)u;  // u >= 0, so trunc == floor
  int v0 = (int)v;
  r.u0 = u0; r.v0 = v0;
  r.u1 = min(u0 + 1, W - 1);
  r.v1 = min(v0 + 1, H - 1);
  r.du = __fadd_rn(u, -(float)u0);
  r.dv = __fadd_rn(v, -(float)v0);
  return r;
}

// Per-XCD-queue item decode. Order: P(f0) P(f1) G(f0) P(f2) G(f1) ...
// P(f7) G(f6) G(f7) -> one frame of prep lead before each gather.
__device__ __forceinline__ void decode_item(int i, bool& isP, int& f, int& j) {
  if (i < 2 * PB) { isP = true; f = i / PB; j = i - f * PB; return; }
  const int k = i - 2 * PB;
  const int b = k / (PB + GB);
  if (b < FPX - 2) {
    const int r = k - b * (PB + GB);
    if (r < GB) { isP = false; f = b; j = r; }
    else        { isP = true;  f = b + 2; j = r - GB; }
    return;
  }
  const int g = k - (FPX - 2) * (PB + GB);
  isP = false; f = (FPX - 2) + g / GB; j = g - (g / GB) * GB;
}

// ============ FUSED persistent pipeline (prep || gather per XCD) ============
// Visibility design:
//  * keys: device-scope atomicMin -> executes at the coherence point, never
//    allocates into a local L2; gather's first (plain) load of a key line
//    happens after the frame's prep completes -> fetches final values.
//  * rec: PLAIN stores; a frame's rec lines are written and read by blocks
//    of the same queue (blockIdx%8), which share one XCD L2 (the mapping the
//    measured swizzle wins rely on). __syncthreads() after the stores drains
//    vmcnt (stores committed to that L2) before done++ is visible.
//  * done/qc: agent-scope relaxed atomics (bypass L1).
//  * No deadlock: queue order puts all of a frame's prep items before its
//    gather items; prep items never block, so dequeued prep always finishes.
__global__ __launch_bounds__(256) void k_fused(
    const float* __restrict__ wp, const float* __restrict__ extr,
    const float* __restrict__ intr, const float* __restrict__ images,
    const float* __restrict__ conf, u64* __restrict__ keys,
    float2* __restrict__ rec, uint32_t* __restrict__ qc,
    uint32_t* __restrict__ done, float* __restrict__ out) {
  __shared__ float4   sc_[TH + 1][TW + 1];
  __shared__ float2   sd_[TH + 1][TW + 1];
  __shared__ uint32_t sh_[TH + 1][TW + 1];
  __shared__ int s_item;

  const int t = threadIdx.x;
  const int xq = blockIdx.x & (NXCD - 1);   // queue id (co-resident L2 group)

  for (;;) {
    __syncthreads();   // protects s_item and LDS arrays across iterations
    if (t == 0)
      s_item = (int)__hip_atomic_fetch_add(&qc[xq], 1u, __ATOMIC_RELAXED,
                                           __HIP_MEMORY_SCOPE_AGENT);
    __syncthreads();
    const int it = s_item;
    if (it >= ITEMS) break;

    bool isP; int f, j;
    decode_item(it, isP, f, j);
    const int s = xq * FPX + f;

    if (isP) {
      // ---------------- prep item: 256 points ----------------
      const int p = j * BLK + t;
      if (p < HW) {
        const float* E = extr + s * 12;
        const float* K = intr + s * 9;
        const int idx = s * HW + p;
        Proj pr = project(wp[idx*3], wp[idx*3+1], wp[idx*3+2], E, K);
        const size_t pix = (size_t)s * HWP + pr.v0 * W + pr.u0;
        atomicMin(&keys[pix], ((u64)enc_f32(pr.z) << 32) | (uint32_t)p);

        const size_t ib = (size_t)s * 3 * HW + p;
        const float vf = pr.valid ? 1.f : 0.f;
        float2* r2 = rec + (size_t)idx * 4;   // 32B stride: line-straddle-free
        r2[0] = make_float2(vf * images[ib],          vf * images[ib + HW]);
        r2[1] = make_float2(vf * images[ib + 2 * HW], vf * conf[idx]);
        r2[2] = make_float2(vf * pr.du,               vf * pr.dv);
      }
      __syncthreads();   // drains vmcnt for ALL threads of the block
      if (t == 0)
        __hip_atomic_fetch_add(&done[s], 1u, __ATOMIC_RELAXED,
                               __HIP_MEMORY_SCOPE_AGENT);
    } else {
      // ---------------- gather item: one 64x4 tile ----------------
      if (t == 0) {
        while (__hip_atomic_load(&done[s], __ATOMIC_RELAXED,
                                 __HIP_MEMORY_SCOPE_AGENT) < (uint32_t)PB)
          __builtin_amdgcn_s_sleep(2);
      }
      __syncthreads();

      const int ty = j / TX, tx = j - ty * TX;
      const int x0 = tx * TW, y0 = ty * TH;
      const u64* kfr = keys + (size_t)s * HWP;
      const float2* rfr = rec + (size_t)s * HW * 4;

      for (int l = t; l < (TH + 1) * (TW + 1); l += BLK) {
        const int rr = l / (TW + 1), cc2 = l - rr * (TW + 1);
        const int yy = y0 - 1 + rr, xx = x0 - 1 + cc2;
        float4 cc = make_float4(0.f, 0.f, 0.f, 0.f);
        float2 dd = make_float2(0.f, 0.f);
        uint32_t hi = 0xFFFFFFFFu;
        if (yy >= 0 && yy < H && xx >= 0 && xx < W) {
          const u64 k = kfr[yy * W + xx];
          if (k != KEY_SENT) {
            hi = (uint32_t)(k >> 32);
            const float2* q = rfr + (size_t)(uint32_t)k * 4;
            const float2 a = q[0], b = q[1], e = q[2];
            cc = make_float4(a.x, a.y, b.x, b.y);
            dd = e;
          }
        }
        sc_[rr][cc2] = cc; sd_[rr][cc2] = dd; sh_[rr][cc2] = hi;
      }
      __syncthreads();

      const int c = t % TW, r = t / TW;   // r in [0,TH)
      const int x = x0 + c, y = y0 + r;
      if (x < W && y < H) {
        const bool ex = (x == W - 1);
        const bool ey = (y == H - 1);
        const float4 cC = sc_[r + 1][c + 1]; const float2 dC = sd_[r + 1][c + 1];
        const float4 cU = sc_[r][c + 1];     const float2 dU = sd_[r][c + 1];
        const float4 cL = sc_[r + 1][c];     const float2 dL = sd_[r + 1][c];
        const float4 cD = sc_[r][c];         const float2 dD = sd_[r][c];
        const uint32_t hi = sh_[r + 1][c + 1];

        const float wC = (ex ? 1.f : 1.f - dC.x) * (ey ? 1.f : 1.f - dC.y);
        const float wU = (ex ? 1.f : 1.f - dU.x) * dU.y;
        const float wL = dL.x * (ey ? 1.f : 1.f - dL.y);
        const float wD = dD.x * dD.y;

        // reference splat-loop order: C(w00), U(w01), L(w10), D(w11)
        const float ar = wC*cC.x + wU*cU.x + wL*cL.x + wD*cD.x;
        const float ag = wC*cC.y + wU*cU.y + wL*cL.y + wD*cD.y;
        const float ab = wC*cC.z + wU*cU.z + wL*cL.z + wD*cD.z;
        const float ac = wC*cC.w + wU*cU.w + wL*cL.w + wD*cD.w;
        const bool over = (ar > 1.f) | (ag > 1.f) | (ab > 1.f);

        float* rgb   = out;
        float* depth = out + (size_t)3 * N;
        float* cbuf  = out + (size_t)4 * N;
        float* mask  = out + (size_t)5 * N;
        const int p = y * W + x;
        const size_t ob = (size_t)s * 3 * HW + p;
        rgb[ob]          = fminf(fmaxf(ar, 0.f), 1.f);
        rgb[ob + HW]     = fminf(fmaxf(ag, 0.f), 1.f);
        rgb[ob + 2*HW]   = fminf(fmaxf(ab, 0.f), 1.f);
        const int i = s * HW + p;
        const bool missed = (hi == 0xFFFFFFFFu);
        depth[i] = missed ? DEPTH_MISS : dec_f32(hi);
        cbuf[i]  = ac;
        mask[i]  = (!missed && !over) ? 1.f : 0.f;
      }
    }
  }
}

// ============== Fallback A1: round-9 two-kernel path (proven) ==============

template <int REC>
__global__ __launch_bounds__(256) void k_prep(
    const float* __restrict__ wp, const float* __restrict__ extr,
    const float* __restrict__ intr, const float* __restrict__ images,
    const float* __restrict__ conf, u64* __restrict__ keys,
    float2* __restrict__ rec) {
  const int nb = PB * S;
  const int o = blockIdx.x;
  const int wg = (o % NXCD) * (nb / NXCD) + o / NXCD;
  const int s  = wg / PB;
  const int p  = (wg - s * PB) * BLK + threadIdx.x;
  if (p >= HW) return;
  const float* E = extr + s * 12;
  const float* K = intr + s * 9;
  const int idx = s * HW + p;
  Proj pr = project(wp[idx*3], wp[idx*3+1], wp[idx*3+2], E, K);
  const size_t pix = (size_t)s * HW + pr.v0 * W + pr.u0;
  atomicMin(&keys[pix], ((u64)enc_f32(pr.z) << 32) | (uint32_t)p);
  const size_t ib = (size_t)s * 3 * HW + p;
  const float vf = pr.valid ? 1.f : 0.f;
  float2* r2 = rec + (size_t)idx * REC;
  r2[0] = make_float2(vf * images[ib],          vf * images[ib + HW]);
  r2[1] = make_float2(vf * images[ib + 2 * HW], vf * conf[idx]);
  r2[2] = make_float2(vf * pr.du,               vf * pr.dv);
}

template <int REC>
__global__ __launch_bounds__(256) void k_gather4(
    const u64* __restrict__ keys, const float2* __restrict__ rec,
    float* __restrict__ out) {
  __shared__ float4   sc[TH + 1][TW + 1];
  __shared__ float2   sd[TH + 1][TW + 1];
  __shared__ uint32_t sh[TH + 1][TW + 1];
  const int nb2 = GB * S;
  const int o = blockIdx.x;
  const int wg = (o % NXCD) * (nb2 / NXCD) + o / NXCD;
  const int s   = wg / GB;
  const int tid = wg - s * GB;
  const int ty  = tid / TX, tx = tid - ty * TX;
  const int x0  = tx * TW, y0 = ty * TH;
  const int t   = threadIdx.x;
  const u64* kfr = keys + (size_t)s * HW;
  const float2* rfr = rec + (size_t)s * HW * REC;

  for (int l = t; l < (TH + 1) * (TW + 1); l += BLK) {
    const int r = l / (TW + 1), c = l - r * (TW + 1);
    const int yy = y0 - 1 + r, xx = x0 - 1 + c;
    float4 cc = make_float4(0.f, 0.f, 0.f, 0.f);
    float2 dd = make_float2(0.f, 0.f);
    uint32_t hi = 0xFFFFFFFFu;
    if (yy >= 0 && yy < H && xx >= 0 && xx < W) {
      const u64 k = kfr[yy * W + xx];
      if (k != KEY_SENT) {
        hi = (uint32_t)(k >> 32);
        const float2* q = rfr + (size_t)(uint32_t)k * REC;
        const float2 a = q[0], b = q[1], e = q[2];
        cc = make_float4(a.x, a.y, b.x, b.y);
        dd = e;
      }
    }
    sc[r][c] = cc; sd[r][c] = dd; sh[r][c] = hi;
  }
  __syncthreads();

  const int c = t % TW, r = t / TW;
  const int x = x0 + c, y = y0 + r;
  if (x >= W || y >= H) return;
  const bool ex = (x == W - 1);
  const bool ey = (y == H - 1);
  const float4 cC = sc[r + 1][c + 1]; const float2 dC = sd[r + 1][c + 1];
  const float4 cU = sc[r][c + 1];     const float2 dU = sd[r][c + 1];
  const float4 cL = sc[r + 1][c];     const float2 dL = sd[r + 1][c];
  const float4 cD = sc[r][c];         const float2 dD = sd[r][c];
  const uint32_t hi = sh[r + 1][c + 1];
  const float wC = (ex ? 1.f : 1.f - dC.x) * (ey ? 1.f : 1.f - dC.y);
  const float wU = (ex ? 1.f : 1.f - dU.x) * dU.y;
  const float wL = dL.x * (ey ? 1.f : 1.f - dL.y);
  const float wD = dD.x * dD.y;
  const float ar = wC*cC.x + wU*cU.x + wL*cL.x + wD*cD.x;
  const float ag = wC*cC.y + wU*cU.y + wL*cL.y + wD*cD.y;
  const float ab = wC*cC.z + wU*cU.z + wL*cL.z + wD*cD.z;
  const float ac = wC*cC.w + wU*cU.w + wL*cL.w + wD*cD.w;
  const bool over = (ar > 1.f) | (ag > 1.f) | (ab > 1.f);

  float* rgb   = out;
  float* depth = out + (size_t)3 * N;
  float* cbuf  = out + (size_t)4 * N;
  float* mask  = out + (size_t)5 * N;
  const int p = y * W + x;
  const size_t ob = (size_t)s * 3 * HW + p;
  rgb[ob]          = fminf(fmaxf(ar, 0.f), 1.f);
  rgb[ob + HW]     = fminf(fmaxf(ag, 0.f), 1.f);
  rgb[ob + 2 * HW] = fminf(fmaxf(ab, 0.f), 1.f);
  const int i = s * HW + p;
  const bool missed = (hi == 0xFFFFFFFFu);
  depth[i] = missed ? DEPTH_MISS : dec_f32(hi);
  cbuf[i]  = ac;
  mask[i]  = (!missed && !over) ? 1.f : 0.f;
}

// ================== Tier C (round-3 scatter, proven, no ws) ==================

__global__ __launch_bounds__(256) void k_depth(
    const float* __restrict__ wp, const float* __restrict__ extr,
    const float* __restrict__ intr, uint32_t* __restrict__ denc) {
  const int s = blockIdx.y;
  const int p = blockIdx.x * blockDim.x + threadIdx.x;
  if (p >= HW) return;
  const float* E = extr + s * 12;
  const float* K = intr + s * 9;
  const int idx = s * HW + p;
  Proj pr = project(wp[idx*3], wp[idx*3+1], wp[idx*3+2], E, K);
  const int pix = s * HW + pr.v0 * W + pr.u0;
  atomicMin(&denc[pix], enc_f32(pr.z));
}

__global__ __launch_bounds__(256) void k_splat(
    const float* __restrict__ wp, const float* __restrict__ extr,
    const float* __restrict__ intr, const float* __restrict__ images,
    const float* __restrict__ conf, const uint32_t* __restrict__ denc,
    float* __restrict__ rgb_buf, float* __restrict__ conf_buf) {
  const int s = blockIdx.y;
  const int p = blockIdx.x * blockDim.x + threadIdx.x;
  if (p >= HW) return;
  const float* E = extr + s * 12;
  const float* K = intr + s * 9;
  const int idx = s * HW + p;
  Proj pr = project(wp[idx*3], wp[idx*3+1], wp[idx*3+2], E, K);
  const int pix0 = s * HW + pr.v0 * W + pr.u0;
  if (!pr.valid) return;
  if (enc_f32(pr.z) != denc[pix0]) return;
  const float du = pr.du, dv = pr.dv;
  const float w00 = (1.0f - du) * (1.0f - dv);
  const float w01 = (1.0f - du) * dv;
  const float w10 = du * (1.0f - dv);
  const float w11 = du * dv;
  const int ibase = s * 3 * HW + p;
  const float r = images[ibase];
  const float g = images[ibase + HW];
  const float b = images[ibase + 2 * HW];
  const float cf = conf[idx];
  const int sbase = s * HW;
  const int cbase = s * 3 * HW;
  #define SPLAT(WGT, PU, PV)                                              \
    if ((WGT) != 0.0f) {                                                  \
      const int q = (PV) * W + (PU);                                      \
      unsafeAtomicAdd(&rgb_buf[cbase + q],          (WGT) * r);           \
      unsafeAtomicAdd(&rgb_buf[cbase + HW + q],     (WGT) * g);           \
      unsafeAtomicAdd(&rgb_buf[cbase + 2 * HW + q], (WGT) * b);           \
      unsafeAtomicAdd(&conf_buf[sbase + q],         (WGT) * cf);          \
    }
  SPLAT(w00, pr.u0, pr.v0)
  SPLAT(w01, pr.u0, pr.v1)
  SPLAT(w10, pr.u1, pr.v0)
  SPLAT(w11, pr.u1, pr.v1)
  #undef SPLAT
}

__global__ __launch_bounds__(256) void k_final(float* __restrict__ out) {
  const int s = blockIdx.y;
  const int p = blockIdx.x * blockDim.x + threadIdx.x;
  if (p >= HW) return;
  float* rgb = out;
  float* depth = out + (size_t)3 * N;
  float* mask = out + (size_t)5 * N;
  uint32_t* denc = (uint32_t*)depth;
  const int cbase = s * 3 * HW + p;
  const float r = rgb[cbase];
  const float g = rgb[cbase + HW];
  const float b = rgb[cbase + 2 * HW];
  const bool over = (r > 1.0f) | (g > 1.0f) | (b > 1.0f);
  rgb[cbase]          = fminf(fmaxf(r, 0.0f), 1.0f);
  rgb[cbase + HW]     = fminf(fmaxf(g, 0.0f), 1.0f);
  rgb[cbase + 2 * HW] = fminf(fmaxf(b, 0.0f), 1.0f);
  const int i = s * HW + p;
  const uint32_t u = denc[i];
  const bool missed = (u == 0xFFFFFFFFu);
  depth[i] = missed ? DEPTH_MISS : dec_f32(u);
  mask[i] = (!missed && !over) ? 1.0f : 0.0f;
}

extern "C" void kernel_launch(void* const* d_in, const int* in_sizes, int n_in,
                              void* d_out, int out_size, void* d_ws, size_t ws_size,
                              hipStream_t stream) {
  const float* images = (const float*)d_in[0];
  const float* wp     = (const float*)d_in[1];
  const float* conf   = (const float*)d_in[2];
  const float* extr   = (const float*)d_in[3];
  const float* intr   = (const float*)d_in[4];
  float* out = (float*)d_out;

  const size_t cnt_bytes   = 4096;                            // qc[8]+done[64]
  const size_t keysp_bytes = (size_t)S * HWP * sizeof(u64);   // padded keys
  const size_t keys_bytes  = (size_t)N * sizeof(u64);
  const size_t rec4_bytes  = (size_t)N * 4 * sizeof(float2);  // 312 MB
  dim3 blk(BLK, 1, 1);

  if (ws_size >= cnt_bytes + keysp_bytes + rec4_bytes) {
    // Fused persistent pipeline: gather hides under the atomic wall.
    uint32_t* cnt  = (uint32_t*)d_ws;
    u64*      keys = (u64*)((char*)d_ws + cnt_bytes);
    float2*   rec  = (float2*)((char*)d_ws + cnt_bytes + keysp_bytes);
    hipMemsetAsync(cnt, 0, cnt_bytes, stream);
    hipMemsetAsync(keys, 0xFF, keysp_bytes, stream);
    hipLaunchKernelGGL(k_fused, dim3(2048), blk, 0, stream, wp, extr, intr,
                       images, conf, keys, rec, cnt, cnt + 8, out);
  } else if (ws_size >= keys_bytes + rec4_bytes) {
    // Round-9 two-kernel path (proven).
    u64*    keys = (u64*)d_ws;
    float2* rec  = (float2*)((char*)d_ws + keys_bytes);
    hipMemsetAsync(keys, 0xFF, keys_bytes, stream);
    hipLaunchKernelGGL((k_prep<4>), dim3(PB * S), blk, 0, stream, wp, extr,
                       intr, images, conf, keys, rec);
    hipLaunchKernelGGL((k_gather4<4>), dim3(GB * S), blk, 0, stream, keys, rec, out);
  } else {
    // Tier C: round-3 scatter path.
    float*    rgb_buf  = out;
    uint32_t* denc     = (uint32_t*)(out + (size_t)3 * N);
    float*    conf_buf = out + (size_t)4 * N;
    hipMemsetAsync(rgb_buf, 0, (size_t)3 * N * sizeof(float), stream);
    hipMemsetAsync(denc, 0xFF, (size_t)N * sizeof(uint32_t), stream);
    hipMemsetAsync(conf_buf, 0, (size_t)N * sizeof(float), stream);
    dim3 grd(PB, S, 1);
    hipLaunchKernelGGL(k_depth, grd, blk, 0, stream, wp, extr, intr, denc);
    hipLaunchKernelGGL(k_splat, grd, blk, 0, stream, wp, extr, intr, images,
                       conf, denc, rgb_buf, conf_buf);
    hipLaunchKernelGGL(k_final, grd, blk, 0, stream, out);
  }
}

// Round 12
// 580.727 us; speedup vs baseline: 5.4864x; 3.6230x over previous
//
#include <hip/hip_runtime.h>
#include <stdint.h>

// Problem constants (match reference setup_inputs)
constexpr int S = 64, H = 294, W = 518;
constexpr int HW = H * W;            // 152292
constexpr int N = S * HW;            // 9746688

constexpr int BLK = 256;
constexpr int PB  = (HW + BLK - 1) / BLK;   // 595 prep items per frame
constexpr int NB  = PB * S;                 // 38080 (divisible by 8)
// Tiled gather geometry: 64x4-pixel tiles.
constexpr int TW = 64, TH = 4;
constexpr int TX = (W + TW - 1) / TW;       // 9
constexpr int TY = (H + TH - 1) / TH;       // 74
constexpr int GB = TX * TY;                 // 666 gather tiles per frame
constexpr int NB2 = GB * S;                 // 42624 (divisible by 8)
constexpr int NXCD = 8;

// Missed-pixel depth sentinel: must stay FINITE under bf16 rounding too
// (FLT_MAX rounds to +inf in bf16 -> harness absmax does inf-inf = nan).
#define DEPTH_MISS 1.0e30f

typedef unsigned long long u64;
constexpr u64 KEY_SENT = 0xFFFFFFFFFFFFFFFFull;

// ---- monotone float<->uint encoding for atomicMin on uint ----
__device__ __forceinline__ uint32_t enc_f32(float f) {
  uint32_t u = __float_as_uint(f);
  return (u & 0x80000000u) ? ~u : (u | 0x80000000u);
}
__device__ __forceinline__ float dec_f32(uint32_t u) {
  uint32_t b = (u & 0x80000000u) ? (u ^ 0x80000000u) : ~u;
  return __uint_as_float(b);
}

struct Proj {
  float z, du, dv;
  int u0, v0, u1, v1;
  bool valid;
};

// Deterministic op sequence (explicit fma) -> identical results wherever a
// point's projection is recomputed (hit test is exact equality on z).
__device__ __forceinline__ Proj project(float px, float py, float pz,
                                        const float* __restrict__ E,
                                        const float* __restrict__ K) {
  Proj r;
  float cx = __fmaf_rn(E[0], px, __fmaf_rn(E[1], py, __fmaf_rn(E[2], pz, E[3])));
  float cy = __fmaf_rn(E[4], px, __fmaf_rn(E[5], py, __fmaf_rn(E[6], pz, E[7])));
  float cz = __fmaf_rn(E[8], px, __fmaf_rn(E[9], py, __fmaf_rn(E[10], pz, E[11])));
  float uh = __fmaf_rn(K[0], cx, __fmaf_rn(K[1], cy, __fmul_rn(K[2], cz)));
  float vh = __fmaf_rn(K[3], cx, __fmaf_rn(K[4], cy, __fmul_rn(K[5], cz)));
  float wh = __fmaf_rn(K[6], cx, __fmaf_rn(K[7], cy, __fmul_rn(K[8], cz)));
  float d  = __fadd_rn(wh, 1e-7f);
  float u  = __fdiv_rn(uh, d);
  float v  = __fdiv_rn(vh, d);
  r.z = cz;
  r.valid = (cz > 0.0f) & (u >= 0.0f) & (u < (float)W) & (v >= 0.0f) & (v < (float)H);
  u = fminf(fmaxf(u, 0.0f), (float)(W - 1));
  v = fminf(fmaxf(v, 0.0f), (float)(H - 1));
  int u0 = (int)u;  // u >= 0, so trunc == floor
  int v0 = (int)v;
  r.u0 = u0; r.v0 = v0;
  r.u1 = min(u0 + 1, W - 1);
  r.v1 = min(v0 + 1, H - 1);
  r.du = __fadd_rn(u, -(float)u0);
  r.dv = __fadd_rn(v, -(float)v0);
  return r;
}

// ================== TIER A: split prep + tiled gather ==================

// Prep with two INDEPENDENT interleaved block groups (no inter-block sync):
//  g==0 blocks: project + scatter atomicMin (the fabric-bound wall)
//  g==1 blocks: project + pack 32B records   (a ~150us write stream)
// The pack stream drains in parallel with the atomic drain instead of
// serializing after it (round-9 k_prep paid it serialized: 402 vs ~360us).
// Both groups compute the identical deterministic projection per point.
__global__ __launch_bounds__(256) void k_prep2(
    const float* __restrict__ wp, const float* __restrict__ extr,
    const float* __restrict__ intr, const float* __restrict__ images,
    const float* __restrict__ conf, u64* __restrict__ keys,
    float2* __restrict__ rec) {
  const int g   = blockIdx.x & 1;
  const int wg0 = blockIdx.x >> 1;
  const int wg  = (wg0 % NXCD) * (NB / NXCD) + wg0 / NXCD;  // XCD swizzle
  const int s   = wg / PB;
  const int p   = (wg - s * PB) * BLK + threadIdx.x;
  if (p >= HW) return;
  const float* E = extr + s * 12;
  const float* K = intr + s * 9;
  const int idx = s * HW + p;
  Proj pr = project(wp[idx*3], wp[idx*3+1], wp[idx*3+2], E, K);

  if (g == 0) {
    const size_t pix = (size_t)s * HW + pr.v0 * W + pr.u0;
    atomicMin(&keys[pix], ((u64)enc_f32(pr.z) << 32) | (uint32_t)p);
  } else {
    const size_t ib = (size_t)s * 3 * HW + p;
    const float vf = pr.valid ? 1.f : 0.f;   // invalid -> zero payload
    float2* r2 = rec + (size_t)idx * 4;      // 32B stride: line-straddle-free
    r2[0] = make_float2(vf * images[ib],          vf * images[ib + HW]);
    r2[1] = make_float2(vf * images[ib + 2 * HW], vf * conf[idx]);
    r2[2] = make_float2(vf * pr.du,               vf * pr.dv);
  }
}

// Tiled gather (round-9, measured ~164us). Block = one 64x4 pixel tile;
// stage the C-winner payloads of the (TH+1)x(TW+1) halo into LDS; each
// pixel reads its C/L/U/D winners from LDS. Out-of-range halo entries get
// ZERO payloads so no alias gates are needed. Edge folding: at x==W-1 the
// winner's u-taps collapse ((1-du)->1); same at y==H-1 for v.
__global__ __launch_bounds__(256) void k_gather4(
    const u64* __restrict__ keys, const float2* __restrict__ rec,
    float* __restrict__ out) {
  __shared__ float4   sc[TH + 1][TW + 1];
  __shared__ float2   sd[TH + 1][TW + 1];
  __shared__ uint32_t sh[TH + 1][TW + 1];
  const int o = blockIdx.x;
  const int wg = (o % NXCD) * (NB2 / NXCD) + o / NXCD;  // XCD swizzle
  const int s   = wg / GB;
  const int tid = wg - s * GB;
  const int ty  = tid / TX, tx = tid - ty * TX;
  const int x0  = tx * TW, y0 = ty * TH;
  const int t   = threadIdx.x;
  const u64* kfr = keys + (size_t)s * HW;
  const float2* rfr = rec + (size_t)s * HW * 4;

  for (int l = t; l < (TH + 1) * (TW + 1); l += BLK) {
    const int r = l / (TW + 1), c = l - r * (TW + 1);
    const int yy = y0 - 1 + r, xx = x0 - 1 + c;
    float4 cc = make_float4(0.f, 0.f, 0.f, 0.f);
    float2 dd = make_float2(0.f, 0.f);
    uint32_t hi = 0xFFFFFFFFu;
    if (yy >= 0 && yy < H && xx >= 0 && xx < W) {
      const u64 k = kfr[yy * W + xx];
      if (k != KEY_SENT) {
        hi = (uint32_t)(k >> 32);
        const float2* q = rfr + (size_t)(uint32_t)k * 4;
        const float2 a = q[0], b = q[1], e = q[2];
        cc = make_float4(a.x, a.y, b.x, b.y);
        dd = e;
      }
    }
    sc[r][c] = cc; sd[r][c] = dd; sh[r][c] = hi;
  }
  __syncthreads();

  const int c = t % TW, r = t / TW;   // r in [0,TH)
  const int x = x0 + c, y = y0 + r;
  if (x >= W || y >= H) return;
  const bool ex = (x == W - 1);
  const bool ey = (y == H - 1);

  const float4 cC = sc[r + 1][c + 1]; const float2 dC = sd[r + 1][c + 1];
  const float4 cU = sc[r][c + 1];     const float2 dU = sd[r][c + 1];
  const float4 cL = sc[r + 1][c];     const float2 dL = sd[r + 1][c];
  const float4 cD = sc[r][c];         const float2 dD = sd[r][c];
  const uint32_t hi = sh[r + 1][c + 1];

  const float wC = (ex ? 1.f : 1.f - dC.x) * (ey ? 1.f : 1.f - dC.y);
  const float wU = (ex ? 1.f : 1.f - dU.x) * dU.y;
  const float wL = dL.x * (ey ? 1.f : 1.f - dL.y);
  const float wD = dD.x * dD.y;

  // accumulate in reference splat-loop order: C(w00), U(w01), L(w10), D(w11)
  const float ar = wC*cC.x + wU*cU.x + wL*cL.x + wD*cD.x;
  const float ag = wC*cC.y + wU*cU.y + wL*cL.y + wD*cD.y;
  const float ab = wC*cC.z + wU*cU.z + wL*cL.z + wD*cD.z;
  const float ac = wC*cC.w + wU*cU.w + wL*cL.w + wD*cD.w;
  const bool over = (ar > 1.f) | (ag > 1.f) | (ab > 1.f);

  float* rgb   = out;
  float* depth = out + (size_t)3 * N;
  float* cbuf  = out + (size_t)4 * N;
  float* mask  = out + (size_t)5 * N;

  const int p = y * W + x;
  const size_t ob = (size_t)s * 3 * HW + p;
  rgb[ob]          = fminf(fmaxf(ar, 0.f), 1.f);
  rgb[ob + HW]     = fminf(fmaxf(ag, 0.f), 1.f);
  rgb[ob + 2 * HW] = fminf(fmaxf(ab, 0.f), 1.f);

  const int i = s * HW + p;
  const bool missed = (hi == 0xFFFFFFFFu);
  depth[i] = missed ? DEPTH_MISS : dec_f32(hi);
  cbuf[i]  = ac;
  mask[i]  = (!missed && !over) ? 1.f : 0.f;
}

// ============== Fallback A1: round-9 combined prep (proven) ==============

__global__ __launch_bounds__(256) void k_prep(
    const float* __restrict__ wp, const float* __restrict__ extr,
    const float* __restrict__ intr, const float* __restrict__ images,
    const float* __restrict__ conf, u64* __restrict__ keys,
    float2* __restrict__ rec) {
  const int o = blockIdx.x;
  const int wg = (o % NXCD) * (NB / NXCD) + o / NXCD;
  const int s  = wg / PB;
  const int p  = (wg - s * PB) * BLK + threadIdx.x;
  if (p >= HW) return;
  const float* E = extr + s * 12;
  const float* K = intr + s * 9;
  const int idx = s * HW + p;
  Proj pr = project(wp[idx*3], wp[idx*3+1], wp[idx*3+2], E, K);
  const size_t pix = (size_t)s * HW + pr.v0 * W + pr.u0;
  atomicMin(&keys[pix], ((u64)enc_f32(pr.z) << 32) | (uint32_t)p);
  const size_t ib = (size_t)s * 3 * HW + p;
  const float vf = pr.valid ? 1.f : 0.f;
  float2* r2 = rec + (size_t)idx * 4;
  r2[0] = make_float2(vf * images[ib],          vf * images[ib + HW]);
  r2[1] = make_float2(vf * images[ib + 2 * HW], vf * conf[idx]);
  r2[2] = make_float2(vf * pr.du,               vf * pr.dv);
}

// ================== Tier C (round-3 scatter, proven, no ws) ==================

__global__ __launch_bounds__(256) void k_depth(
    const float* __restrict__ wp, const float* __restrict__ extr,
    const float* __restrict__ intr, uint32_t* __restrict__ denc) {
  const int s = blockIdx.y;
  const int p = blockIdx.x * blockDim.x + threadIdx.x;
  if (p >= HW) return;
  const float* E = extr + s * 12;
  const float* K = intr + s * 9;
  const int idx = s * HW + p;
  Proj pr = project(wp[idx*3], wp[idx*3+1], wp[idx*3+2], E, K);
  const int pix = s * HW + pr.v0 * W + pr.u0;
  atomicMin(&denc[pix], enc_f32(pr.z));
}

__global__ __launch_bounds__(256) void k_splat(
    const float* __restrict__ wp, const float* __restrict__ extr,
    const float* __restrict__ intr, const float* __restrict__ images,
    const float* __restrict__ conf, const uint32_t* __restrict__ denc,
    float* __restrict__ rgb_buf, float* __restrict__ conf_buf) {
  const int s = blockIdx.y;
  const int p = blockIdx.x * blockDim.x + threadIdx.x;
  if (p >= HW) return;
  const float* E = extr + s * 12;
  const float* K = intr + s * 9;
  const int idx = s * HW + p;
  Proj pr = project(wp[idx*3], wp[idx*3+1], wp[idx*3+2], E, K);
  const int pix0 = s * HW + pr.v0 * W + pr.u0;
  if (!pr.valid) return;
  if (enc_f32(pr.z) != denc[pix0]) return;
  const float du = pr.du, dv = pr.dv;
  const float w00 = (1.0f - du) * (1.0f - dv);
  const float w01 = (1.0f - du) * dv;
  const float w10 = du * (1.0f - dv);
  const float w11 = du * dv;
  const int ibase = s * 3 * HW + p;
  const float r = images[ibase];
  const float g = images[ibase + HW];
  const float b = images[ibase + 2 * HW];
  const float cf = conf[idx];
  const int sbase = s * HW;
  const int cbase = s * 3 * HW;
  #define SPLAT(WGT, PU, PV)                                              \
    if ((WGT) != 0.0f) {                                                  \
      const int q = (PV) * W + (PU);                                      \
      unsafeAtomicAdd(&rgb_buf[cbase + q],          (WGT) * r);           \
      unsafeAtomicAdd(&rgb_buf[cbase + HW + q],     (WGT) * g);           \
      unsafeAtomicAdd(&rgb_buf[cbase + 2 * HW + q], (WGT) * b);           \
      unsafeAtomicAdd(&conf_buf[sbase + q],         (WGT) * cf);          \
    }
  SPLAT(w00, pr.u0, pr.v0)
  SPLAT(w01, pr.u0, pr.v1)
  SPLAT(w10, pr.u1, pr.v0)
  SPLAT(w11, pr.u1, pr.v1)
  #undef SPLAT
}

__global__ __launch_bounds__(256) void k_final(float* __restrict__ out) {
  const int s = blockIdx.y;
  const int p = blockIdx.x * blockDim.x + threadIdx.x;
  if (p >= HW) return;
  float* rgb = out;
  float* depth = out + (size_t)3 * N;
  float* mask = out + (size_t)5 * N;
  uint32_t* denc = (uint32_t*)depth;
  const int cbase = s * 3 * HW + p;
  const float r = rgb[cbase];
  const float g = rgb[cbase + HW];
  const float b = rgb[cbase + 2 * HW];
  const bool over = (r > 1.0f) | (g > 1.0f) | (b > 1.0f);
  rgb[cbase]          = fminf(fmaxf(r, 0.0f), 1.0f);
  rgb[cbase + HW]     = fminf(fmaxf(g, 0.0f), 1.0f);
  rgb[cbase + 2 * HW] = fminf(fmaxf(b, 0.0f), 1.0f);
  const int i = s * HW + p;
  const uint32_t u = denc[i];
  const bool missed = (u == 0xFFFFFFFFu);
  depth[i] = missed ? DEPTH_MISS : dec_f32(u);
  mask[i] = (!missed && !over) ? 1.0f : 0.0f;
}

extern "C" void kernel_launch(void* const* d_in, const int* in_sizes, int n_in,
                              void* d_out, int out_size, void* d_ws, size_t ws_size,
                              hipStream_t stream) {
  const float* images = (const float*)d_in[0];
  const float* wp     = (const float*)d_in[1];
  const float* conf   = (const float*)d_in[2];
  const float* extr   = (const float*)d_in[3];
  const float* intr   = (const float*)d_in[4];
  float* out = (float*)d_out;

  const size_t keys_bytes = (size_t)N * sizeof(u64);          // 78 MB
  const size_t rec4_bytes = (size_t)N * 4 * sizeof(float2);   // 312 MB
  dim3 blk(BLK, 1, 1);

  if (ws_size >= keys_bytes + rec4_bytes) {
    // Tier A: split prep (atomic blocks || pack blocks) + tiled gather.
    u64*    keys = (u64*)d_ws;
    float2* rec  = (float2*)((char*)d_ws + keys_bytes);
    hipMemsetAsync(keys, 0xFF, keys_bytes, stream);
    hipLaunchKernelGGL(k_prep2, dim3(2 * NB), blk, 0, stream, wp, extr, intr,
                       images, conf, keys, rec);
    hipLaunchKernelGGL(k_gather4, dim3(NB2), blk, 0, stream, keys, rec, out);
  } else {
    // Tier C: round-3 scatter path.
    float*    rgb_buf  = out;
    uint32_t* denc     = (uint32_t*)(out + (size_t)3 * N);
    float*    conf_buf = out + (size_t)4 * N;
    hipMemsetAsync(rgb_buf, 0, (size_t)3 * N * sizeof(float), stream);
    hipMemsetAsync(denc, 0xFF, (size_t)N * sizeof(uint32_t), stream);
    hipMemsetAsync(conf_buf, 0, (size_t)N * sizeof(float), stream);
    dim3 grd(PB, S, 1);
    hipLaunchKernelGGL(k_depth, grd, blk, 0, stream, wp, extr, intr, denc);
    hipLaunchKernelGGL(k_splat, grd, blk, 0, stream, wp, extr, intr, images,
                       conf, denc, rgb_buf, conf_buf);
    hipLaunchKernelGGL(k_final, grd, blk, 0, stream, out);
  }
}